// Round 6
// baseline (208.885 us; speedup 1.0000x reference)
//
#include <hip/hip_runtime.h>
#include <hip/hip_bf16.h>
#include <stdint.h>

#define DI __device__ __forceinline__

typedef __attribute__((ext_vector_type(8))) short bf16x8;
typedef __attribute__((ext_vector_type(4))) float f32x4;

static constexpr int Bx = 16, Cx = 512, Nx = 4096;

// async global->LDS, 16B per lane. LDS dst must be the WAVE-UNIFORM base;
// HW adds lane*16. Global src is per-lane.
DI void gload_lds16(const void* gsrc, void* ldst) {
  __builtin_amdgcn_global_load_lds(
      (const __attribute__((address_space(1))) uint32_t*)gsrc,
      (__attribute__((address_space(3))) uint32_t*)ldst, 16, 0, 0);
}

// ---------------------------------------------------------------------------
// Kernel 1: fp32 x -> bf16 Xb [B][C][N] and bf16 XbT [B][N][C]
// ---------------------------------------------------------------------------
__global__ __launch_bounds__(256) void k_cast_transpose(
    const float* __restrict__ x,
    __hip_bfloat16* __restrict__ xb,
    __hip_bfloat16* __restrict__ xbt) {
  __shared__ __hip_bfloat16 tile[64][65];
  const int b = blockIdx.z;
  const int c0 = blockIdx.x * 64;
  const int n0 = blockIdx.y * 64;
  const int t = threadIdx.x;
  const int r = t >> 2;          // 0..63
  const int q = (t & 3) * 16;    // 0,16,32,48

  const float* xp = x + ((size_t)b * Cx + (c0 + r)) * Nx + (n0 + q);
  alignas(16) __hip_bfloat16 v[16];
#pragma unroll
  for (int j = 0; j < 4; ++j) {
    float4 f = *(const float4*)(xp + j * 4);
    v[j * 4 + 0] = __float2bfloat16(f.x);
    v[j * 4 + 1] = __float2bfloat16(f.y);
    v[j * 4 + 2] = __float2bfloat16(f.z);
    v[j * 4 + 3] = __float2bfloat16(f.w);
  }
  __hip_bfloat16* xbp = xb + ((size_t)b * Cx + (c0 + r)) * Nx + (n0 + q);
  *(uint4*)xbp = *(const uint4*)&v[0];
  *(uint4*)(xbp + 8) = *(const uint4*)&v[8];
#pragma unroll
  for (int j = 0; j < 16; ++j) tile[r][q + j] = v[j];
  __syncthreads();
  alignas(16) __hip_bfloat16 o[16];
#pragma unroll
  for (int j = 0; j < 16; ++j) o[j] = tile[q + j][r];
  __hip_bfloat16* xtp = xbt + ((size_t)b * Nx + (n0 + r)) * Cx + (c0 + q);
  *(uint4*)xtp = *(const uint4*)&o[0];
  *(uint4*)(xtp + 8) = *(const uint4*)&o[8];
}

// ---------------------------------------------------------------------------
// NT bf16 GEMM: 128x128 tile, BK=32, 4 waves (2x2 of 64x64).
// QUAD-buffered LDS, prefetch distance 3, counted vmcnt:
//   step it: s_waitcnt vmcnt(8) [tiles it+1,it+2 stay in flight; tile it
//   landed] -> s_barrier [tile it visible to all waves AND compute(it-1)
//   done in all waves, so restaging buffer (it+3)&3 == buffer computed at
//   it-1 is safe] -> STAGE(it+3) -> COMPUTE(it).
// Latency budget = 3 full steps (~900+ cy) >= HBM latency.
// Epilogue drains vmcnt 4 -> 0 (exact counts; tile it is always landed).
// T2 LDS swizzle both-sides. T1 XCD-chunked grid swizzle.
// LDS-staged coalesced epilogue (flat float4 row stores, 1KB/wave/instr).
// EPI: out = xres + beta*acc.
// ---------------------------------------------------------------------------
template <bool EPI>
__global__ __launch_bounds__(256) void k_gemm_nt(
    const __hip_bfloat16* A, const __hip_bfloat16* Bt,
    float* __restrict__ Co, const float* __restrict__ xres,
    const float* __restrict__ betap, int M, int Nd, int K, int kLen,
    int nsplit, int gx, int gy) {
  __shared__ alignas(16) char lds[65536];  // 4 bufs x (sA 8K + sB 8K)

  // XCD-chunked bijective swizzle (grid divisible by 8)
  const int nblk = gridDim.x;
  int s = (blockIdx.x & 7) * (nblk >> 3) + (blockIdx.x >> 3);
  const int bxi = s % gx;
  s /= gx;
  const int byi = s % gy;
  s /= gy;
  const int b = s / nsplit;
  const int kz = s - b * nsplit;

  const int t = threadIdx.x;
  const int lane = t & 63;
  const int wave = t >> 6;
  const int wr = (wave >> 1) * 64;
  const int wc = (wave & 1) * 64;
  const int fr = lane & 15;
  const int fq = lane >> 4;
  const int perm = (fr >> 1) & 3;  // read-side swizzle

  const size_t aBase =
      (size_t)b * M * K + (size_t)(bxi * 128) * K + (size_t)kz * kLen;
  const size_t bBase =
      (size_t)b * Nd * K + (size_t)(byi * 128) * K + (size_t)kz * kLen;
  const int srow = t >> 2;
  // source k-offset pre-swizzled (matches read-side XOR)
  const int skoff = (((t & 3) ^ ((t >> 3) & 3)) * 8);

  f32x4 acc[4][4];
#pragma unroll
  for (int m = 0; m < 4; ++m)
#pragma unroll
    for (int n = 0; n < 4; ++n) acc[m][n] = {0.f, 0.f, 0.f, 0.f};

  auto STAGE = [&](char* bufbase, int kt) {
    char* base = bufbase + (wave << 10);
    gload_lds16(A + aBase + (size_t)srow * K + kt + skoff, base);
    gload_lds16(A + aBase + (size_t)(srow + 64) * K + kt + skoff, base + 4096);
    gload_lds16(Bt + bBase + (size_t)srow * K + kt + skoff, base + 8192);
    gload_lds16(Bt + bBase + (size_t)(srow + 64) * K + kt + skoff,
                base + 12288);
  };

  auto COMPUTE = [&](const char* p) {
    const __hip_bfloat16* sA = (const __hip_bfloat16*)p;
    const __hip_bfloat16* sB = (const __hip_bfloat16*)(p + 8192);
    bf16x8 af[4], bfr[4];
#pragma unroll
    for (int m = 0; m < 4; ++m)
      af[m] = *(const bf16x8*)&sA[(wr + m * 16 + fr) * 32 + ((fq ^ perm) * 8)];
#pragma unroll
    for (int n = 0; n < 4; ++n)
      bfr[n] = *(const bf16x8*)&sB[(wc + n * 16 + fr) * 32 + ((fq ^ perm) * 8)];
#pragma unroll
    for (int m = 0; m < 4; ++m)
#pragma unroll
      for (int n = 0; n < 4; ++n)
        acc[m][n] = __builtin_amdgcn_mfma_f32_16x16x32_bf16(af[m], bfr[n],
                                                            acc[m][n], 0, 0, 0);
  };

  const int nt = kLen >> 5;  // BK=32 steps; nt >= 16 for all our shapes
  char* q0 = lds;
  char* q1 = lds + 16384;
  char* q2 = lds + 32768;
  char* q3 = lds + 49152;
  STAGE(q0, 0);
  STAGE(q1, 32);
  STAGE(q2, 64);
  for (int it = 0; it < nt - 2; ++it) {
    // tile it landed; tiles it+1, it+2 (8 loads) stay in flight
    asm volatile("s_waitcnt vmcnt(8)" ::: "memory");
    __builtin_amdgcn_s_barrier();
    __builtin_amdgcn_sched_barrier(0);
    if (it + 3 < nt) STAGE(q3, (it + 3) << 5);
    COMPUTE(q0);
    char* tmp = q0; q0 = q1; q1 = q2; q2 = q3; q3 = tmp;
  }
  // it = nt-2: only tile nt-1 (4 loads) may remain in flight
  asm volatile("s_waitcnt vmcnt(4)" ::: "memory");
  __builtin_amdgcn_s_barrier();
  __builtin_amdgcn_sched_barrier(0);
  COMPUTE(q0);
  { char* tmp = q0; q0 = q1; q1 = q2; q2 = q3; q3 = tmp; }
  // it = nt-1: drain
  asm volatile("s_waitcnt vmcnt(0)" ::: "memory");
  __builtin_amdgcn_s_barrier();
  __builtin_amdgcn_sched_barrier(0);
  COMPUTE(q0);

  // ---- LDS-staged coalesced epilogue ----
  __syncthreads();  // all waves done reading K-loop LDS
  const float beta = EPI ? betap[0] : 0.f;
  float* lds_f = (float*)lds;  // 64 rows x 128 cols fp32 = 32 KiB
  float* cb = Co + ((size_t)kz * Bx + b) * M * Nd;
  const float* xb = EPI ? (xres + (size_t)b * M * Nd) : nullptr;

#pragma unroll
  for (int h = 0; h < 2; ++h) {
    if (wr == h * 64) {
#pragma unroll
      for (int m = 0; m < 4; ++m)
#pragma unroll
        for (int n = 0; n < 4; ++n)
#pragma unroll
          for (int r = 0; r < 4; ++r)
            lds_f[(m * 16 + fq * 4 + r) * 128 + (wc + n * 16 + fr)] =
                acc[m][n][r];
    }
    __syncthreads();
#pragma unroll
    for (int j = 0; j < 8; ++j) {
      const int f4 = j * 256 + t;       // flat float4 index in 64x128 chunk
      const int rloc = f4 >> 5;         // 32 float4 per row
      const int c0 = (f4 & 31) << 2;    // col in floats
      const int grow = bxi * 128 + h * 64 + rloc;
      const int gcol = byi * 128 + c0;
      f32x4 v = *(const f32x4*)&lds_f[rloc * 128 + c0];
      const size_t gidx = (size_t)grow * Nd + gcol;
      if (EPI) {
        f32x4 xv = *(const f32x4*)&xb[gidx];
#pragma unroll
        for (int e = 0; e < 4; ++e) v[e] = fmaf(beta, v[e], xv[e]);
      }
      *(f32x4*)&cb[gidx] = v;
    }
    __syncthreads();
  }
}

// ---------------------------------------------------------------------------
// Kernel 3: sum split-K partials, then row softmax of (-S):
// attn = exp(min(S_row) - S) / sum.  One wave per row, bf16 out.
// ---------------------------------------------------------------------------
__global__ __launch_bounds__(256) void k_softmax(
    const float* __restrict__ Sp, __hip_bfloat16* __restrict__ At, int nsplit,
    size_t pstride) {
  const int row = blockIdx.x * 4 + (threadIdx.x >> 6);
  const int lane = threadIdx.x & 63;
  float v[8] = {0.f, 0.f, 0.f, 0.f, 0.f, 0.f, 0.f, 0.f};
  for (int sp = 0; sp < nsplit; ++sp) {
    const float* p = Sp + sp * pstride + (size_t)row * Cx + lane * 8;
    float4 f0 = *(const float4*)p;
    float4 f1 = *(const float4*)(p + 4);
    v[0] += f0.x; v[1] += f0.y; v[2] += f0.z; v[3] += f0.w;
    v[4] += f1.x; v[5] += f1.y; v[6] += f1.z; v[7] += f1.w;
  }
  float mn = v[0];
#pragma unroll
  for (int j = 1; j < 8; ++j) mn = fminf(mn, v[j]);
#pragma unroll
  for (int off = 32; off; off >>= 1) mn = fminf(mn, __shfl_xor(mn, off));
  float w[8];
  float sum = 0.f;
#pragma unroll
  for (int j = 0; j < 8; ++j) {
    w[j] = __expf(mn - v[j]);  // <= 1, no overflow
    sum += w[j];
  }
#pragma unroll
  for (int off = 32; off; off >>= 1) sum += __shfl_xor(sum, off);
  const float inv = 1.f / sum;
  alignas(16) __hip_bfloat16 o[8];
#pragma unroll
  for (int j = 0; j < 8; ++j) o[j] = __float2bfloat16(w[j] * inv);
  *(uint4*)(At + (size_t)row * Cx + lane * 8) = *(const uint4*)o;
}

// ---------------------------------------------------------------------------
extern "C" void kernel_launch(void* const* d_in, const int* in_sizes, int n_in,
                              void* d_out, int out_size, void* d_ws,
                              size_t ws_size, hipStream_t stream) {
  const float* x = (const float*)d_in[0];
  const float* beta = (const float*)d_in[1];
  float* out = (float*)d_out;
  char* ws = (char*)d_ws;

  const size_t MB = (size_t)1 << 20;
  // ws layout: Xb 64 MiB | XbT 64 MiB | At 8 MiB.
  // Split-K partials live in d_out (134 MiB scratch until GEMM2 overwrites).
  const int nsplit = 4;
  __hip_bfloat16* xb = (__hip_bfloat16*)ws;
  __hip_bfloat16* xbt = (__hip_bfloat16*)(ws + 64 * MB);
  __hip_bfloat16* At = (__hip_bfloat16*)(ws + 128 * MB);
  float* Sp = out;
  const size_t pstride = (size_t)Bx * Cx * Cx;

  k_cast_transpose<<<dim3(Cx / 64, Nx / 64, Bx), 256, 0, stream>>>(x, xb, xbt);
  // GEMM1: S_partial[kz] = Xb * Xb^T over K-chunk kz. grid 1024 blocks.
  k_gemm_nt<false><<<(Cx / 128) * (Cx / 128) * Bx * nsplit, 256, 0, stream>>>(
      xb, xb, Sp, nullptr, nullptr, Cx, Cx, Nx, Nx / nsplit, nsplit, Cx / 128,
      Cx / 128);
  k_softmax<<<(Bx * Cx) / 4, 256, 0, stream>>>(Sp, At, nsplit, pstride);
  // GEMM2: out = beta*(attn * XbT^T) + x. grid 2048 blocks.
  k_gemm_nt<true><<<(Cx / 128) * (Nx / 128) * Bx, 256, 0, stream>>>(
      At, xbt, out, x, beta, Cx, Nx, Cx, Cx, 1, Cx / 128, Nx / 128);
}

// Round 7
// 201.376 us; speedup vs baseline: 1.0373x; 1.0373x over previous
//
#include <hip/hip_runtime.h>
#include <hip/hip_bf16.h>
#include <stdint.h>

#define DI __device__ __forceinline__

typedef __attribute__((ext_vector_type(8))) short bf16x8;
typedef __attribute__((ext_vector_type(4))) float f32x4;

static constexpr int Bx = 16, Cx = 512, Nx = 4096;

// async global->LDS, 16B per lane. LDS dst must be the WAVE-UNIFORM base;
// HW adds lane*16. Global src is per-lane.
DI void gload_lds16(const void* gsrc, void* ldst) {
  __builtin_amdgcn_global_load_lds(
      (const __attribute__((address_space(1))) uint32_t*)gsrc,
      (__attribute__((address_space(3))) uint32_t*)ldst, 16, 0, 0);
}

// ---------------------------------------------------------------------------
// Kernel 1: fp32 x -> bf16 Xb [B][C][N] and bf16 XbT [B][N][C]  (unchanged)
// ---------------------------------------------------------------------------
__global__ __launch_bounds__(256) void k_cast_transpose(
    const float* __restrict__ x,
    __hip_bfloat16* __restrict__ xb,
    __hip_bfloat16* __restrict__ xbt) {
  __shared__ __hip_bfloat16 tile[64][65];
  const int b = blockIdx.z;
  const int c0 = blockIdx.x * 64;
  const int n0 = blockIdx.y * 64;
  const int t = threadIdx.x;
  const int r = t >> 2;          // 0..63
  const int q = (t & 3) * 16;    // 0,16,32,48

  const float* xp = x + ((size_t)b * Cx + (c0 + r)) * Nx + (n0 + q);
  alignas(16) __hip_bfloat16 v[16];
#pragma unroll
  for (int j = 0; j < 4; ++j) {
    float4 f = *(const float4*)(xp + j * 4);
    v[j * 4 + 0] = __float2bfloat16(f.x);
    v[j * 4 + 1] = __float2bfloat16(f.y);
    v[j * 4 + 2] = __float2bfloat16(f.z);
    v[j * 4 + 3] = __float2bfloat16(f.w);
  }
  __hip_bfloat16* xbp = xb + ((size_t)b * Cx + (c0 + r)) * Nx + (n0 + q);
  *(uint4*)xbp = *(const uint4*)&v[0];
  *(uint4*)(xbp + 8) = *(const uint4*)&v[8];
#pragma unroll
  for (int j = 0; j < 16; ++j) tile[r][q + j] = v[j];
  __syncthreads();
  alignas(16) __hip_bfloat16 o[16];
#pragma unroll
  for (int j = 0; j < 16; ++j) o[j] = tile[q + j][r];
  __hip_bfloat16* xtp = xbt + ((size_t)b * Nx + (n0 + r)) * Cx + (c0 + q);
  *(uint4*)xtp = *(const uint4*)&o[0];
  *(uint4*)(xtp + 8) = *(const uint4*)&o[8];
}

// ---------------------------------------------------------------------------
// GEMM1 (unchanged from R6): 128x128 tile, quad-buffered, counted vmcnt.
// ---------------------------------------------------------------------------
__global__ __launch_bounds__(256) void k_gemm_nt(
    const __hip_bfloat16* A, const __hip_bfloat16* Bt,
    float* __restrict__ Co, int M, int Nd, int K, int kLen,
    int nsplit, int gx, int gy) {
  __shared__ alignas(16) char lds[65536];  // 4 bufs x (sA 8K + sB 8K)

  const int nblk = gridDim.x;
  int s = (blockIdx.x & 7) * (nblk >> 3) + (blockIdx.x >> 3);
  const int bxi = s % gx;
  s /= gx;
  const int byi = s % gy;
  s /= gy;
  const int b = s / nsplit;
  const int kz = s - b * nsplit;

  const int t = threadIdx.x;
  const int lane = t & 63;
  const int wave = t >> 6;
  const int wr = (wave >> 1) * 64;
  const int wc = (wave & 1) * 64;
  const int fr = lane & 15;
  const int fq = lane >> 4;
  const int perm = (fr >> 1) & 3;

  const size_t aBase =
      (size_t)b * M * K + (size_t)(bxi * 128) * K + (size_t)kz * kLen;
  const size_t bBase =
      (size_t)b * Nd * K + (size_t)(byi * 128) * K + (size_t)kz * kLen;
  const int srow = t >> 2;
  const int skoff = (((t & 3) ^ ((t >> 3) & 3)) * 8);

  f32x4 acc[4][4];
#pragma unroll
  for (int m = 0; m < 4; ++m)
#pragma unroll
    for (int n = 0; n < 4; ++n) acc[m][n] = {0.f, 0.f, 0.f, 0.f};

  auto STAGE = [&](char* bufbase, int kt) {
    char* base = bufbase + (wave << 10);
    gload_lds16(A + aBase + (size_t)srow * K + kt + skoff, base);
    gload_lds16(A + aBase + (size_t)(srow + 64) * K + kt + skoff, base + 4096);
    gload_lds16(Bt + bBase + (size_t)srow * K + kt + skoff, base + 8192);
    gload_lds16(Bt + bBase + (size_t)(srow + 64) * K + kt + skoff,
                base + 12288);
  };

  auto COMPUTE = [&](const char* p) {
    const __hip_bfloat16* sA = (const __hip_bfloat16*)p;
    const __hip_bfloat16* sB = (const __hip_bfloat16*)(p + 8192);
    bf16x8 af[4], bfr[4];
#pragma unroll
    for (int m = 0; m < 4; ++m)
      af[m] = *(const bf16x8*)&sA[(wr + m * 16 + fr) * 32 + ((fq ^ perm) * 8)];
#pragma unroll
    for (int n = 0; n < 4; ++n)
      bfr[n] = *(const bf16x8*)&sB[(wc + n * 16 + fr) * 32 + ((fq ^ perm) * 8)];
#pragma unroll
    for (int m = 0; m < 4; ++m)
#pragma unroll
      for (int n = 0; n < 4; ++n)
        acc[m][n] = __builtin_amdgcn_mfma_f32_16x16x32_bf16(af[m], bfr[n],
                                                            acc[m][n], 0, 0, 0);
  };

  const int nt = kLen >> 5;
  char* q0 = lds;
  char* q1 = lds + 16384;
  char* q2 = lds + 32768;
  char* q3 = lds + 49152;
  STAGE(q0, 0);
  STAGE(q1, 32);
  STAGE(q2, 64);
  for (int it = 0; it < nt - 2; ++it) {
    asm volatile("s_waitcnt vmcnt(8)" ::: "memory");
    __builtin_amdgcn_s_barrier();
    __builtin_amdgcn_sched_barrier(0);
    if (it + 3 < nt) STAGE(q3, (it + 3) << 5);
    COMPUTE(q0);
    char* tmp = q0; q0 = q1; q1 = q2; q2 = q3; q3 = tmp;
  }
  asm volatile("s_waitcnt vmcnt(4)" ::: "memory");
  __builtin_amdgcn_s_barrier();
  __builtin_amdgcn_sched_barrier(0);
  COMPUTE(q0);
  { char* tmp = q0; q0 = q1; q1 = q2; q2 = q3; q3 = tmp; }
  asm volatile("s_waitcnt vmcnt(0)" ::: "memory");
  __builtin_amdgcn_s_barrier();
  __builtin_amdgcn_sched_barrier(0);
  COMPUTE(q0);

  // LDS-staged coalesced epilogue
  __syncthreads();
  float* lds_f = (float*)lds;
  float* cb = Co + ((size_t)kz * Bx + b) * M * Nd;
#pragma unroll
  for (int h = 0; h < 2; ++h) {
    if (wr == h * 64) {
#pragma unroll
      for (int m = 0; m < 4; ++m)
#pragma unroll
        for (int n = 0; n < 4; ++n)
#pragma unroll
          for (int r = 0; r < 4; ++r)
            lds_f[(m * 16 + fq * 4 + r) * 128 + (wc + n * 16 + fr)] =
                acc[m][n][r];
    }
    __syncthreads();
#pragma unroll
    for (int j = 0; j < 8; ++j) {
      const int f4 = j * 256 + t;
      const int rloc = f4 >> 5;
      const int c0 = (f4 & 31) << 2;
      const int grow = bxi * 128 + h * 64 + rloc;
      const int gcol = byi * 128 + c0;
      f32x4 v = *(const f32x4*)&lds_f[rloc * 128 + c0];
      *(f32x4*)&cb[(size_t)grow * Nd + gcol] = v;
    }
    __syncthreads();
  }
}

// ---------------------------------------------------------------------------
// GEMM2, 8-phase 256^2 template (T3+T4+T2+T5).
// C[512x4096] = At[512x512] x XbT[4096x512]^T per batch; out = x + beta*C.
// BM=BN=256, BK=64, 8 waves (2M x 4N), 512 thr, nt=8 K-tiles.
// LDS per buf: A half0[128][64] | A half1 | B half0 | B half1 (16 KiB each);
// 2 bufs = 128 KiB. Half-tile stage stream, per-tile order (B0,B1,A0,A1),
// lead 2 halves: tile-k phases stage {A0,A1 of k+1 (other buf); B0,B1 of
// k+2 (same buf, B dead after phase 0)} -> race-free. vmcnt(4) at tile
// close guarantees next tile landed (FIFO: only last 2 halves outstanding);
// vmcnt(0) at close of tile nt-2 (no stages during final tile).
// Phase q: reads A m=2q,2q+1 (x2 kk); q==0 also reads all B (8 reads);
// stage 1 half; barrier; lgkmcnt(0)+sched_barrier (rule 18); setprio(1);
// 16 MFMA; setprio(0); [tile-close vmcnt]; barrier.
// LDS swizzle: byte ^= (row&7)<<4 on ds_read; staging source pre-swizzled
// (granule g holds logical slot (g&7)^(row&7)) so linear gload_lds works.
// ---------------------------------------------------------------------------
__global__ __launch_bounds__(512) void k_gemm2_8ph(
    const __hip_bfloat16* __restrict__ A,   // At  [B][512][512]
    const __hip_bfloat16* __restrict__ Bt,  // XbT [B][4096][512]
    float* __restrict__ Co, const float* __restrict__ xres,
    const float* __restrict__ betap) {
  __shared__ alignas(16) char lds[131072];
  constexpr int K = 512, NT = 8;  // K-tiles of 64

  // XCD-chunked swizzle; decode bxi fastest (B-panel L2 reuse across bxi)
  const int nblk = gridDim.x;  // 512
  int s = (blockIdx.x & 7) * (nblk >> 3) + (blockIdx.x >> 3);
  const int bxi = s & 1;  s >>= 1;
  const int byi = s & 15; s >>= 4;
  const int b = s;  // 0..15

  const int t = threadIdx.x;
  const int lane = t & 63;
  const int wave = t >> 6;   // 0..7
  const int wm = wave >> 2;  // 0..1 (row half)
  const int wn = wave & 3;   // 0..3 (col quarter)
  const int fr = lane & 15;
  const int fq = lane >> 4;

  const size_t aBase = ((size_t)b * 512 + bxi * 256) * K;
  const size_t bBase = ((size_t)b * 4096 + byi * 256) * K;

  // staging: thread t covers linear granules t and t+512 of a 128x64 half.
  // linear granule g holds logical (row=g>>3, slot=(g&7)^(row&7)).
  const int r0 = t >> 3, c0 = ((t & 7) ^ (r0 & 7)) * 8;
  const int r1 = (t + 512) >> 3, c1 = (((t + 512) & 7) ^ (r1 & 7)) * 8;

  auto STAGE = [&](int sp) {
    if (sp >= 4 * NT) return;
    const int st = sp >> 2;  // stream tile
    const int se = sp & 3;   // 0,1 = B half; 2,3 = A half
    const int kt = st << 6;
    char* dst;
    const __hip_bfloat16* src;
    if (se < 2) {
      dst = lds + (st & 1) * 65536 + 32768 + se * 16384 + (wave << 10);
      src = Bt + bBase + (size_t)(se * 128) * K + kt;
    } else {
      dst = lds + (st & 1) * 65536 + (se - 2) * 16384 + (wave << 10);
      src = A + aBase + (size_t)((se - 2) * 128) * K + kt;
    }
    gload_lds16(src + (size_t)r0 * K + c0, dst);
    gload_lds16(src + (size_t)r1 * K + c1, dst + 8192);
  };

  f32x4 acc[8][4];
#pragma unroll
  for (int m = 0; m < 8; ++m)
#pragma unroll
    for (int n = 0; n < 4; ++n) acc[m][n] = {0.f, 0.f, 0.f, 0.f};

  bf16x8 bB[8];  // B frags, held across the tile's 4 phases

  // prologue: 6 halves (tile0 complete + B0,B1 of tile1), wait tile0
  for (int sp = 0; sp < 6; ++sp) STAGE(sp);
  asm volatile("s_waitcnt vmcnt(4)" ::: "memory");
  __builtin_amdgcn_s_barrier();
  __builtin_amdgcn_sched_barrier(0);

  for (int k = 0; k < NT; ++k) {
    const int buf = (k & 1) << 16;  // byte offset of current buffer
#pragma unroll
    for (int q = 0; q < 4; ++q) {
      if (q == 0) {
#pragma unroll
        for (int n = 0; n < 4; ++n)
#pragma unroll
          for (int kk = 0; kk < 2; ++kk) {
            const int brow = wn * 64 + n * 16 + fr;  // 0..255
            bB[n * 2 + kk] = *(const bf16x8*)(lds + buf + 32768 +
                (brow >> 7) * 16384 + (brow & 127) * 128 +
                ((kk * 64 + fq * 16) ^ ((brow & 7) << 4)));
          }
      }
      bf16x8 aA[4];
#pragma unroll
      for (int ml = 0; ml < 2; ++ml)
#pragma unroll
        for (int kk = 0; kk < 2; ++kk) {
          const int row = (q * 2 + ml) * 16 + fr;  // 0..127 within half
          aA[ml * 2 + kk] = *(const bf16x8*)(lds + buf + wm * 16384 +
              row * 128 + ((kk * 64 + fq * 16) ^ ((row & 7) << 4)));
        }
      STAGE(6 + k * 4 + q);
      __builtin_amdgcn_s_barrier();  // split read/issue cluster from MFMA
      asm volatile("s_waitcnt lgkmcnt(0)" ::: "memory");
      __builtin_amdgcn_sched_barrier(0);  // rule 18: pin MFMA after wait
      __builtin_amdgcn_s_setprio(1);
#pragma unroll
      for (int ml = 0; ml < 2; ++ml)
#pragma unroll
        for (int n = 0; n < 4; ++n)
#pragma unroll
          for (int kk = 0; kk < 2; ++kk)
            acc[q * 2 + ml][n] = __builtin_amdgcn_mfma_f32_16x16x32_bf16(
                aA[ml * 2 + kk], bB[n * 2 + kk], acc[q * 2 + ml][n], 0, 0, 0);
      __builtin_amdgcn_s_setprio(0);
      if (q == 3) {
        // publish tile k+1 for next iteration's reads
        if (k < NT - 2) {
          asm volatile("s_waitcnt vmcnt(4)" ::: "memory");
        } else if (k == NT - 2) {
          asm volatile("s_waitcnt vmcnt(0)" ::: "memory");
        }
      }
      __builtin_amdgcn_s_barrier();
      __builtin_amdgcn_sched_barrier(0);
    }
  }

  // epilogue: out = xres + beta*acc
  const float beta = betap[0];
  const size_t obase = (size_t)b * 512 * 4096;
#pragma unroll
  for (int m = 0; m < 8; ++m) {
    const int row = bxi * 256 + wm * 128 + m * 16 + fq * 4;
#pragma unroll
    for (int n = 0; n < 4; ++n) {
      const int col = byi * 256 + wn * 64 + n * 16 + fr;
#pragma unroll
      for (int r = 0; r < 4; ++r) {
        const size_t idx = obase + (size_t)(row + r) * 4096 + col;
        Co[idx] = fmaf(beta, acc[m][n][r], xres[idx]);
      }
    }
  }
}

// ---------------------------------------------------------------------------
// Kernel 3: sum split-K partials, then row softmax of (-S)  (unchanged)
// ---------------------------------------------------------------------------
__global__ __launch_bounds__(256) void k_softmax(
    const float* __restrict__ Sp, __hip_bfloat16* __restrict__ At, int nsplit,
    size_t pstride) {
  const int row = blockIdx.x * 4 + (threadIdx.x >> 6);
  const int lane = threadIdx.x & 63;
  float v[8] = {0.f, 0.f, 0.f, 0.f, 0.f, 0.f, 0.f, 0.f};
  for (int sp = 0; sp < nsplit; ++sp) {
    const float* p = Sp + sp * pstride + (size_t)row * Cx + lane * 8;
    float4 f0 = *(const float4*)p;
    float4 f1 = *(const float4*)(p + 4);
    v[0] += f0.x; v[1] += f0.y; v[2] += f0.z; v[3] += f0.w;
    v[4] += f1.x; v[5] += f1.y; v[6] += f1.z; v[7] += f1.w;
  }
  float mn = v[0];
#pragma unroll
  for (int j = 1; j < 8; ++j) mn = fminf(mn, v[j]);
#pragma unroll
  for (int off = 32; off; off >>= 1) mn = fminf(mn, __shfl_xor(mn, off));
  float w[8];
  float sum = 0.f;
#pragma unroll
  for (int j = 0; j < 8; ++j) {
    w[j] = __expf(mn - v[j]);
    sum += w[j];
  }
#pragma unroll
  for (int off = 32; off; off >>= 1) sum += __shfl_xor(sum, off);
  const float inv = 1.f / sum;
  alignas(16) __hip_bfloat16 o[8];
#pragma unroll
  for (int j = 0; j < 8; ++j) o[j] = __float2bfloat16(w[j] * inv);
  *(uint4*)(At + (size_t)row * Cx + lane * 8) = *(const uint4*)o;
}

// ---------------------------------------------------------------------------
extern "C" void kernel_launch(void* const* d_in, const int* in_sizes, int n_in,
                              void* d_out, int out_size, void* d_ws,
                              size_t ws_size, hipStream_t stream) {
  const float* x = (const float*)d_in[0];
  const float* beta = (const float*)d_in[1];
  float* out = (float*)d_out;
  char* ws = (char*)d_ws;

  const size_t MB = (size_t)1 << 20;
  const int nsplit = 4;
  __hip_bfloat16* xb = (__hip_bfloat16*)ws;
  __hip_bfloat16* xbt = (__hip_bfloat16*)(ws + 64 * MB);
  __hip_bfloat16* At = (__hip_bfloat16*)(ws + 128 * MB);
  float* Sp = out;  // split-K partials scratch in d_out
  const size_t pstride = (size_t)Bx * Cx * Cx;

  k_cast_transpose<<<dim3(Cx / 64, Nx / 64, Bx), 256, 0, stream>>>(x, xb, xbt);
  k_gemm_nt<<<(Cx / 128) * (Cx / 128) * Bx * nsplit, 256, 0, stream>>>(
      xb, xb, Sp, Cx, Cx, Nx, Nx / nsplit, nsplit, Cx / 128, Cx / 128);
  k_softmax<<<(Bx * Cx) / 4, 256, 0, stream>>>(Sp, At, nsplit, pstride);
  // GEMM2: 2 x 16 x 16 = 512 blocks, 512 threads
  k_gemm2_8ph<<<(Cx / 256) * (Nx / 256) * Bx, 512, 0, stream>>>(
      At, xbt, out, x, beta);
}

// Round 8
// 194.247 us; speedup vs baseline: 1.0754x; 1.0367x over previous
//
#include <hip/hip_runtime.h>
#include <hip/hip_bf16.h>
#include <stdint.h>

#define DI __device__ __forceinline__

typedef __attribute__((ext_vector_type(8))) short bf16x8;
typedef __attribute__((ext_vector_type(4))) float f32x4;

static constexpr int Bx = 16, Cx = 512, Nx = 4096;

// async global->LDS, 16B per lane. LDS dst must be the WAVE-UNIFORM base;
// HW adds lane*16. Global src is per-lane.
DI void gload_lds16(const void* gsrc, void* ldst) {
  __builtin_amdgcn_global_load_lds(
      (const __attribute__((address_space(1))) uint32_t*)gsrc,
      (__attribute__((address_space(3))) uint32_t*)ldst, 16, 0, 0);
}

// ---------------------------------------------------------------------------
// Kernel 1: fp32 x -> bf16 Xb [B][C][N] and bf16 XbT [B][N][C]  (unchanged)
// ---------------------------------------------------------------------------
__global__ __launch_bounds__(256) void k_cast_transpose(
    const float* __restrict__ x,
    __hip_bfloat16* __restrict__ xb,
    __hip_bfloat16* __restrict__ xbt) {
  __shared__ __hip_bfloat16 tile[64][65];
  const int b = blockIdx.z;
  const int c0 = blockIdx.x * 64;
  const int n0 = blockIdx.y * 64;
  const int t = threadIdx.x;
  const int r = t >> 2;          // 0..63
  const int q = (t & 3) * 16;    // 0,16,32,48

  const float* xp = x + ((size_t)b * Cx + (c0 + r)) * Nx + (n0 + q);
  alignas(16) __hip_bfloat16 v[16];
#pragma unroll
  for (int j = 0; j < 4; ++j) {
    float4 f = *(const float4*)(xp + j * 4);
    v[j * 4 + 0] = __float2bfloat16(f.x);
    v[j * 4 + 1] = __float2bfloat16(f.y);
    v[j * 4 + 2] = __float2bfloat16(f.z);
    v[j * 4 + 3] = __float2bfloat16(f.w);
  }
  __hip_bfloat16* xbp = xb + ((size_t)b * Cx + (c0 + r)) * Nx + (n0 + q);
  *(uint4*)xbp = *(const uint4*)&v[0];
  *(uint4*)(xbp + 8) = *(const uint4*)&v[8];
#pragma unroll
  for (int j = 0; j < 16; ++j) tile[r][q + j] = v[j];
  __syncthreads();
  alignas(16) __hip_bfloat16 o[16];
#pragma unroll
  for (int j = 0; j < 16; ++j) o[j] = tile[q + j][r];
  __hip_bfloat16* xtp = xbt + ((size_t)b * Nx + (n0 + r)) * Cx + (c0 + q);
  *(uint4*)xtp = *(const uint4*)&o[0];
  *(uint4*)(xtp + 8) = *(const uint4*)&o[8];
}

// ---------------------------------------------------------------------------
// NT bf16 GEMM: 128x256 tile, BK=32, 8 waves (2x4 of 64x64), 512 threads.
// TRIPLE-buffered LDS (24 KiB/buf: A[128][32] 8K | B[256][32] 16K) = 72 KiB
// -> 2 blocks/CU, 16 waves/CU: one block's staging/epilogue memory overlaps
// the other's MFMA (the R7 diagnosis: unoverlapped bulk memory phases).
// Counted vmcnt, distance 2 (verified R4 skeleton, 3 loads/stage):
//   step it: vmcnt(3) [tile it landed; tile it+1's 3 stay in flight]
//   -> s_barrier -> STAGE(it+2) -> COMPUTE(it).
// T2 LDS XOR-swizzle both-sides (verified R3: 0 conflicts).
// LDS-staged coalesced epilogue (verified R5): flat float4 rows.
// EPI: out = xres + beta*acc.
// ---------------------------------------------------------------------------
template <bool EPI>
__global__ __launch_bounds__(512, 4) void k_gemm_nt(
    const __hip_bfloat16* A, const __hip_bfloat16* Bt,
    float* __restrict__ Co, const float* __restrict__ xres,
    const float* __restrict__ betap, int M, int Nd, int K, int kLen,
    int nsplit, int gx, int gy) {
  __shared__ alignas(16) char lds[73728];  // 3 bufs x 24 KiB

  // XCD-chunked bijective swizzle (grid divisible by 8)
  const int nblk = gridDim.x;
  int s = (blockIdx.x & 7) * (nblk >> 3) + (blockIdx.x >> 3);
  const int bxi = s % gx;
  s /= gx;
  const int byi = s % gy;
  s /= gy;
  const int b = s / nsplit;
  const int kz = s - b * nsplit;

  const int t = threadIdx.x;
  const int lane = t & 63;
  const int wave = t >> 6;   // 0..7
  const int wm = wave >> 2;  // 0..1: row half (64 rows each)
  const int wn = wave & 3;   // 0..3: col quarter (64 cols each)
  const int fr = lane & 15;
  const int fq = lane >> 4;
  const int perm = (fr >> 1) & 3;  // read-side swizzle

  const size_t aBase =
      (size_t)b * M * K + (size_t)(bxi * 128) * K + (size_t)kz * kLen;
  const size_t bBase =
      (size_t)b * Nd * K + (size_t)(byi * 256) * K + (size_t)kz * kLen;
  const int srow = t >> 2;  // 0..127
  // source k-granule pre-swizzled: (t>>3)&3 == (srow>>1)&3, matches read XOR
  const int skoff = (((t & 3) ^ ((t >> 3) & 3)) * 8);

  f32x4 acc[4][4];
#pragma unroll
  for (int m = 0; m < 4; ++m)
#pragma unroll
    for (int n = 0; n < 4; ++n) acc[m][n] = {0.f, 0.f, 0.f, 0.f};

  auto STAGE = [&](char* buf, int kt) {
    // A: 128 rows x 64B = 8 KiB; each wave w covers rows [16w,16w+16)
    gload_lds16(A + aBase + (size_t)srow * K + kt + skoff,
                buf + (wave << 10));
    // B: 256 rows; rows 0..127 then 128..255 (swizzle invariant under +128)
    gload_lds16(Bt + bBase + (size_t)srow * K + kt + skoff,
                buf + 8192 + (wave << 10));
    gload_lds16(Bt + bBase + (size_t)(srow + 128) * K + kt + skoff,
                buf + 16384 + (wave << 10));
  };

  auto COMPUTE = [&](const char* p) {
    const __hip_bfloat16* sA = (const __hip_bfloat16*)p;
    const __hip_bfloat16* sB = (const __hip_bfloat16*)(p + 8192);
    bf16x8 af[4], bfr[4];
#pragma unroll
    for (int m = 0; m < 4; ++m)
      af[m] =
          *(const bf16x8*)&sA[(wm * 64 + m * 16 + fr) * 32 + ((fq ^ perm) * 8)];
#pragma unroll
    for (int n = 0; n < 4; ++n)
      bfr[n] =
          *(const bf16x8*)&sB[(wn * 64 + n * 16 + fr) * 32 + ((fq ^ perm) * 8)];
#pragma unroll
    for (int m = 0; m < 4; ++m)
#pragma unroll
      for (int n = 0; n < 4; ++n)
        acc[m][n] = __builtin_amdgcn_mfma_f32_16x16x32_bf16(af[m], bfr[n],
                                                            acc[m][n], 0, 0, 0);
  };

  const int nt = kLen >> 5;  // BK=32 steps
  char* p0 = lds;
  char* p1 = lds + 24576;
  char* p2 = lds + 49152;
  STAGE(p0, 0);
  STAGE(p1, 32);
  for (int it = 0; it < nt - 1; ++it) {
    // tile it landed; tile it+1's 3 loads stay in flight
    asm volatile("s_waitcnt vmcnt(3)" ::: "memory");
    __builtin_amdgcn_s_barrier();
    __builtin_amdgcn_sched_barrier(0);
    if (it + 2 < nt) STAGE(p2, (it + 2) << 5);
    COMPUTE(p0);
    char* tmp = p0; p0 = p1; p1 = p2; p2 = tmp;
  }
  asm volatile("s_waitcnt vmcnt(0)" ::: "memory");
  __builtin_amdgcn_s_barrier();
  __builtin_amdgcn_sched_barrier(0);
  COMPUTE(p0);

  // ---- LDS-staged coalesced epilogue (64x256 fp32 chunks = 64 KiB) ----
  __syncthreads();
  const float beta = EPI ? betap[0] : 0.f;
  float* lds_f = (float*)lds;
  float* cb = Co + ((size_t)kz * Bx + b) * M * Nd;
  const float* xb = EPI ? (xres + (size_t)b * M * Nd) : nullptr;

#pragma unroll
  for (int h = 0; h < 2; ++h) {
    if (wm == h) {
#pragma unroll
      for (int m = 0; m < 4; ++m)
#pragma unroll
        for (int n = 0; n < 4; ++n)
#pragma unroll
          for (int r = 0; r < 4; ++r)
            lds_f[(m * 16 + fq * 4 + r) * 256 + (wn * 64 + n * 16 + fr)] =
                acc[m][n][r];
    }
    __syncthreads();
#pragma unroll
    for (int j = 0; j < 8; ++j) {
      const int f4 = j * 512 + t;       // flat float4 index in 64x256 chunk
      const int rloc = f4 >> 6;         // 64 float4 per row
      const int c0 = (f4 & 63) << 2;    // col in floats
      const int grow = bxi * 128 + h * 64 + rloc;
      const int gcol = byi * 256 + c0;
      f32x4 v = *(const f32x4*)&lds_f[rloc * 256 + c0];
      const size_t gidx = (size_t)grow * Nd + gcol;
      if (EPI) {
        f32x4 xv = *(const f32x4*)&xb[gidx];
#pragma unroll
        for (int e = 0; e < 4; ++e) v[e] = fmaf(beta, v[e], xv[e]);
      }
      *(f32x4*)&cb[gidx] = v;
    }
    __syncthreads();
  }
}

// ---------------------------------------------------------------------------
// Kernel 3: sum split-K partials, then row softmax of (-S)  (unchanged)
// ---------------------------------------------------------------------------
__global__ __launch_bounds__(256) void k_softmax(
    const float* __restrict__ Sp, __hip_bfloat16* __restrict__ At, int nsplit,
    size_t pstride) {
  const int row = blockIdx.x * 4 + (threadIdx.x >> 6);
  const int lane = threadIdx.x & 63;
  float v[8] = {0.f, 0.f, 0.f, 0.f, 0.f, 0.f, 0.f, 0.f};
  for (int sp = 0; sp < nsplit; ++sp) {
    const float* p = Sp + sp * pstride + (size_t)row * Cx + lane * 8;
    float4 f0 = *(const float4*)p;
    float4 f1 = *(const float4*)(p + 4);
    v[0] += f0.x; v[1] += f0.y; v[2] += f0.z; v[3] += f0.w;
    v[4] += f1.x; v[5] += f1.y; v[6] += f1.z; v[7] += f1.w;
  }
  float mn = v[0];
#pragma unroll
  for (int j = 1; j < 8; ++j) mn = fminf(mn, v[j]);
#pragma unroll
  for (int off = 32; off; off >>= 1) mn = fminf(mn, __shfl_xor(mn, off));
  float w[8];
  float sum = 0.f;
#pragma unroll
  for (int j = 0; j < 8; ++j) {
    w[j] = __expf(mn - v[j]);
    sum += w[j];
  }
#pragma unroll
  for (int off = 32; off; off >>= 1) sum += __shfl_xor(sum, off);
  const float inv = 1.f / sum;
  alignas(16) __hip_bfloat16 o[8];
#pragma unroll
  for (int j = 0; j < 8; ++j) o[j] = __float2bfloat16(w[j] * inv);
  *(uint4*)(At + (size_t)row * Cx + lane * 8) = *(const uint4*)o;
}

// ---------------------------------------------------------------------------
extern "C" void kernel_launch(void* const* d_in, const int* in_sizes, int n_in,
                              void* d_out, int out_size, void* d_ws,
                              size_t ws_size, hipStream_t stream) {
  const float* x = (const float*)d_in[0];
  const float* beta = (const float*)d_in[1];
  float* out = (float*)d_out;
  char* ws = (char*)d_ws;

  const size_t MB = (size_t)1 << 20;
  const int nsplit = 4;
  __hip_bfloat16* xb = (__hip_bfloat16*)ws;
  __hip_bfloat16* xbt = (__hip_bfloat16*)(ws + 64 * MB);
  __hip_bfloat16* At = (__hip_bfloat16*)(ws + 128 * MB);
  float* Sp = out;  // split-K partials scratch in d_out (dead after softmax)
  const size_t pstride = (size_t)Bx * Cx * Cx;

  k_cast_transpose<<<dim3(Cx / 64, Nx / 64, Bx), 256, 0, stream>>>(x, xb, xbt);
  // GEMM1: 4 x 2 x 16 x 4 = 512 blocks x 512 thr (2 blocks/CU)
  k_gemm_nt<false><<<(Cx / 128) * (Cx / 256) * Bx * nsplit, 512, 0, stream>>>(
      xb, xb, Sp, nullptr, nullptr, Cx, Cx, Nx, Nx / nsplit, nsplit, Cx / 128,
      Cx / 256);
  k_softmax<<<(Bx * Cx) / 4, 256, 0, stream>>>(Sp, At, nsplit, pstride);
  // GEMM2: 4 x 16 x 16 = 1024 blocks x 512 thr (2 blocks/CU)
  k_gemm_nt<true><<<(Cx / 128) * (Nx / 256) * Bx, 512, 0, stream>>>(
      At, xbt, out, x, beta, Cx, Nx, Cx, Cx, 1, Cx / 128, Nx / 256);
}